// Round 5
// baseline (947.217 us; speedup 1.0000x reference)
//
#include <hip/hip_runtime.h>
#include <math.h>

#define NN 50000
#define NE 800000
#define NG 512
#define LRELU 0.2f
#define LN_EPS 1e-5f
#define GCAP 128   // max supported in-degree (data Poisson(16), max ~45)

typedef __attribute__((ext_vector_type(8))) short short8;
typedef __attribute__((ext_vector_type(4))) float f32x4;

// ---------------------------------------------------------------- CSR build
__global__ void hist_kernel(const int* __restrict__ dst, int* __restrict__ deg) {
    int e = blockIdx.x * blockDim.x + threadIdx.x;
    if (e < NE) atomicAdd(&deg[dst[e]], 1);
}

__global__ __launch_bounds__(1024) void scan1(const int* __restrict__ deg,
                                              int* __restrict__ excl,
                                              int* __restrict__ bsum, int n) {
    __shared__ int s[1024];
    int tid = threadIdx.x;
    int gid = blockIdx.x * 1024 + tid;
    int v = (gid < n) ? deg[gid] : 0;
    s[tid] = v;
    __syncthreads();
    for (int off = 1; off < 1024; off <<= 1) {
        int t = (tid >= off) ? s[tid - off] : 0;
        __syncthreads();
        s[tid] += t;
        __syncthreads();
    }
    if (gid < n) excl[gid] = s[tid] - v;
    if (tid == 1023) bsum[blockIdx.x] = s[1023];
}

__global__ void scan2(int* __restrict__ bsum, int nb) {
    if (threadIdx.x == 0 && blockIdx.x == 0) {
        int run = 0;
        for (int b = 0; b < nb; b++) { int t = bsum[b]; bsum[b] = run; run += t; }
    }
}

__global__ __launch_bounds__(1024) void scan3(int* __restrict__ row_ptr,
                                              int* __restrict__ cursor,
                                              const int* __restrict__ bsum, int n) {
    int tid = threadIdx.x;
    int gid = blockIdx.x * 1024 + tid;
    if (gid < n) {
        int v = row_ptr[gid] + bsum[blockIdx.x];
        row_ptr[gid] = v;
        cursor[gid] = v;
    }
    if (gid == 0) row_ptr[n] = NE;
}

__global__ void scatter_kernel(const int* __restrict__ src, const int* __restrict__ dst,
                               int* __restrict__ cursor, int* __restrict__ col_src,
                               const int* __restrict__ batch, int* __restrict__ gcnt) {
    int e = blockIdx.x * blockDim.x + threadIdx.x;
    if (e < NE) {
        int pos = atomicAdd(&cursor[dst[e]], 1);
        col_src[pos] = src[e];
    }
    if (e < NN) atomicAdd(&gcnt[batch[e]], 1);
}

// ---------------------------------------------------------------- bf16 split helpers
__device__ inline void split_bf16(float v, ushort& h, ushort& l) {
    unsigned ub = __float_as_uint(v);
    unsigned hh = (ub + 0x7FFFu + ((ub >> 16) & 1u)) >> 16;
    float vh = __uint_as_float(hh << 16);
    float r = v - vh;
    unsigned ur = __float_as_uint(r);
    unsigned ll = (ur + 0x7FFFu + ((ur >> 16) & 1u)) >> 16;
    h = (ushort)hh; l = (ushort)ll;
}

__global__ __launch_bounds__(256) void prep_w(const float* __restrict__ Wl0,
                                              const float* __restrict__ Wr0,
                                              const float* __restrict__ Wl1,
                                              const float* __restrict__ Wr1,
                                              const float* __restrict__ Wl2,
                                              const float* __restrict__ Wr2,
                                              ushort* __restrict__ wt) {
    int id = blockIdx.x * 256 + threadIdx.x;
    const float* Wl; const float* Wr; int K, half, rel; ushort* hi; int losz;
    if (id < 65536) {                    // layer 0: K=128, N=512 (256+256)
        rel = id; K = 128; half = 256; Wl = Wl0; Wr = Wr0;
        hi = wt; losz = 65536;
    } else if (id < 98304) {             // layer 1: K=256, N=128 (64+64)
        rel = id - 65536; K = 256; half = 64; Wl = Wl1; Wr = Wr1;
        hi = wt + 131072; losz = 32768;
    } else if (id < 106496) {            // layer 2: K=64, N=128 (64+64)
        rel = id - 98304; K = 64; half = 64; Wl = Wl2; Wr = Wr2;
        hi = wt + 196608; losz = 8192;
    } else return;
    int n = rel / K, k = rel - n * K;
    float v = (n < half) ? Wl[k * half + n] : Wr[k * half + (n - half)];
    ushort h, l;
    split_bf16(v, h, l);
    hi[rel] = h;
    hi[losz + rel] = l;
}

// split x -> hi/lo planes
__global__ __launch_bounds__(256) void split_x(const float* __restrict__ x,
                                               ushort* __restrict__ Xh,
                                               ushort* __restrict__ Xl) {
    int i = blockIdx.x * 256 + threadIdx.x;
    if (i >= NN * 32) return;   // float4 units
    float4 v = ((const float4*)x)[i];
    ushort4 h, l;
    split_bf16(v.x, h.x, l.x);
    split_bf16(v.y, h.y, l.y);
    split_bf16(v.z, h.z, l.z);
    split_bf16(v.w, h.w, l.w);
    ((ushort4*)Xh)[i] = h;
    ((ushort4*)Xl)[i] = l;
}

// ---------------------------------------------------------------- MFMA GEMM (bf16 hi/lo planes)
// C[M x Ncol] = (Ah+Al) @ (Bh+Bl)^T + bias ; block tile 128x128, 4 waves 2x2,
// wave tile 64x64 => 48 MFMA per 16 ds_read_b128.
__global__ __launch_bounds__(256) void gemm_bf16(const ushort* __restrict__ Ah,
                                                 const ushort* __restrict__ Al,
                                                 const ushort* __restrict__ Bh,
                                                 const ushort* __restrict__ Bl,
                                                 const float* __restrict__ biasL,
                                                 const float* __restrict__ biasR,
                                                 int halfN,
                                                 float* __restrict__ C,
                                                 int M, int Ncol, int K) {
    __shared__ ushort sA[2][128][40];   // [plane][row][k], row stride 80 B
    __shared__ ushort sB[2][128][40];
    const int tid = threadIdx.x;
    const int w = tid >> 6, lane = tid & 63;
    const int row0 = blockIdx.x * 128;
    const int col0 = blockIdx.y * 128;
    const int wr = (w & 1) * 64, wc = (w >> 1) * 64;
    const int fm = lane & 15;
    const int fk8 = (lane >> 4) * 8;
    f32x4 acc[4][4] = {};

    for (int k0 = 0; k0 < K; k0 += 32) {
        __syncthreads();
        #pragma unroll
        for (int p = 0; p < 2; p++) {
            const ushort* Ap = p ? Al : Ah;
            const ushort* Bp = p ? Bl : Bh;
            #pragma unroll
            for (int it = 0; it < 2; it++) {
                int idx = it * 256 + tid;           // 0..511
                int r = idx >> 2, q = (idx & 3) * 8;
                int grow = row0 + r;
                short8 va = {};
                if (grow < M) va = *(const short8*)&Ap[(size_t)grow * K + k0 + q];
                *(short8*)&sA[p][r][q] = va;
                *(short8*)&sB[p][r][q] = *(const short8*)&Bp[(size_t)(col0 + r) * K + k0 + q];
            }
        }
        __syncthreads();
        short8 ah[4], al[4];
        #pragma unroll
        for (int m = 0; m < 4; m++) {
            ah[m] = *(const short8*)&sA[0][wr + m * 16 + fm][fk8];
            al[m] = *(const short8*)&sA[1][wr + m * 16 + fm][fk8];
        }
        #pragma unroll
        for (int c = 0; c < 4; c++) {
            short8 bh = *(const short8*)&sB[0][wc + c * 16 + fm][fk8];
            short8 bl = *(const short8*)&sB[1][wc + c * 16 + fm][fk8];
            #pragma unroll
            for (int m = 0; m < 4; m++) {
                acc[m][c] = __builtin_amdgcn_mfma_f32_16x16x32_bf16(ah[m], bh, acc[m][c], 0, 0, 0);
                acc[m][c] = __builtin_amdgcn_mfma_f32_16x16x32_bf16(al[m], bh, acc[m][c], 0, 0, 0);
                acc[m][c] = __builtin_amdgcn_mfma_f32_16x16x32_bf16(ah[m], bl, acc[m][c], 0, 0, 0);
            }
        }
    }
    // epilogue: C/D layout col=lane&15, row=(lane>>4)*4+reg
    const int rbase = (lane >> 4) * 4;
    #pragma unroll
    for (int c = 0; c < 4; c++) {
        int col = col0 + wc + c * 16 + fm;
        float bv = (col < halfN) ? biasL[col] : biasR[col - halfN];
        #pragma unroll
        for (int m = 0; m < 4; m++) {
            #pragma unroll
            for (int r = 0; r < 4; r++) {
                int grow = row0 + wr + m * 16 + rbase + r;
                if (grow < M) C[(size_t)grow * Ncol + col] = acc[m][c][r] + bv;
            }
        }
    }
}

// ---------------------------------------------------------------- fused GATv2, H=4 (HC=256)
__global__ __launch_bounds__(256) void gat4(const float* __restrict__ xlr,  // [N][512] = xl|xr
                                            const float* __restrict__ att,
                                            const float* __restrict__ bias,
                                            const int* __restrict__ row_ptr,
                                            const int* __restrict__ col_src,
                                            float* __restrict__ out,
                                            float* __restrict__ bk) {
    __shared__ float4 sxr[64];
    __shared__ float4 satt[64];
    __shared__ int    scol[GCAP];
    __shared__ float  smw[4][64];
    __shared__ float  slw[4][64];
    __shared__ float4 sacc[4][64];
    const int n = blockIdx.x;
    const int tid = threadIdx.x;
    const int w = tid >> 6, lane = tid & 63;
    const int base = row_ptr[n];
    int deg = row_ptr[n + 1] - base;
    if (deg > GCAP) deg = GCAP;
    if (tid < 64) {
        sxr[tid]  = ((const float4*)(xlr + (size_t)n * 512 + 256))[tid];
        satt[tid] = ((const float4*)att)[tid];
    }
    if (tid < deg) scol[tid] = col_src[base + tid];
    __syncthreads();
    const float4 rxr = sxr[lane], ratt = satt[lane];

    float m = -INFINITY, l = 0.f;
    float4 acc = {0.f, 0.f, 0.f, 0.f};
    for (int j = w; j < deg; j += 4) {
        int s = scol[j];
        float4 xv = ((const float4*)(xlr + (size_t)s * 512))[lane];
        float vx = xv.x + rxr.x; vx = (vx > 0.f) ? vx : LRELU * vx;
        float vy = xv.y + rxr.y; vy = (vy > 0.f) ? vy : LRELU * vy;
        float vz = xv.z + rxr.z; vz = (vz > 0.f) ? vz : LRELU * vz;
        float vw = xv.w + rxr.w; vw = (vw > 0.f) ? vw : LRELU * vw;
        float p = vx * ratt.x + vy * ratt.y + vz * ratt.z + vw * ratt.w;
        p += __shfl_xor(p, 1, 64);
        p += __shfl_xor(p, 2, 64);
        p += __shfl_xor(p, 4, 64);
        p += __shfl_xor(p, 8, 64);
        float mn = fmaxf(m, p);
        float sc = __expf(m - mn);
        float ep = __expf(p - mn);
        l = l * sc + ep;
        acc.x = fmaf(acc.x, sc, ep * xv.x);
        acc.y = fmaf(acc.y, sc, ep * xv.y);
        acc.z = fmaf(acc.z, sc, ep * xv.z);
        acc.w = fmaf(acc.w, sc, ep * xv.w);
        m = mn;
    }
    smw[w][lane] = m;
    slw[w][lane] = l;
    sacc[w][lane] = acc;
    __syncthreads();
    if (w == 0) {
        float m0 = smw[0][lane], m1 = smw[1][lane], m2 = smw[2][lane], m3 = smw[3][lane];
        float ms = fmaxf(fmaxf(m0, m1), fmaxf(m2, m3));
        float c0 = (m0 == -INFINITY) ? 0.f : __expf(m0 - ms);
        float c1 = (m1 == -INFINITY) ? 0.f : __expf(m1 - ms);
        float c2 = (m2 == -INFINITY) ? 0.f : __expf(m2 - ms);
        float c3 = (m3 == -INFINITY) ? 0.f : __expf(m3 - ms);
        float lt = slw[0][lane] * c0 + slw[1][lane] * c1 + slw[2][lane] * c2 + slw[3][lane] * c3;
        float rden = (lt > 0.f) ? 1.f / lt : 0.f;
        float4 a0 = sacc[0][lane], a1 = sacc[1][lane], a2 = sacc[2][lane], a3 = sacc[3][lane];
        float4 bv = ((const float4*)bias)[lane];
        float4 o;
        o.x = (a0.x * c0 + a1.x * c1 + a2.x * c2 + a3.x * c3) * rden + bv.x;
        o.y = (a0.y * c0 + a1.y * c1 + a2.y * c2 + a3.y * c3) * rden + bv.y;
        o.z = (a0.z * c0 + a1.z * c1 + a2.z * c2 + a3.z * c3) * rden + bv.z;
        o.w = (a0.w * c0 + a1.w * c1 + a2.w * c2 + a3.w * c3) * rden + bv.w;
        ((float4*)(out + (size_t)n * 256))[lane] = o;
        float s = o.x + o.y + o.z + o.w;
        float s2 = o.x * o.x + o.y * o.y + o.z * o.z + o.w * o.w;
        #pragma unroll
        for (int off = 32; off > 0; off >>= 1) {
            s  += __shfl_xor(s, off, 64);
            s2 += __shfl_xor(s2, off, 64);
        }
        if (lane == 0) {
            int b = n & 63;
            atomicAdd(&bk[b * 4], s);
            atomicAdd(&bk[b * 4 + 1], s2);
        }
    }
}

// ---------------------------------------------------------------- fused GATv2, H=1 (HC=64)
__global__ __launch_bounds__(64) void gat1(const float* __restrict__ xlr,  // [N][128] = xl|xr
                                           const float* __restrict__ att,
                                           const float* __restrict__ bias,
                                           const int* __restrict__ row_ptr,
                                           const int* __restrict__ col_src,
                                           float* __restrict__ out,
                                           float* __restrict__ bk) {
    __shared__ int    scol[GCAP];
    __shared__ float  smw[4][16];
    __shared__ float  slw[4][16];
    __shared__ float4 sacc[4][16];
    const int n = blockIdx.x;
    const int lane = threadIdx.x;
    const int base = row_ptr[n];
    int deg = row_ptr[n + 1] - base;
    if (deg > GCAP) deg = GCAP;
    for (int j = lane; j < deg; j += 64) scol[j] = col_src[base + j];
    const int g = lane >> 4, li = lane & 15;
    const float4 rxr  = ((const float4*)(xlr + (size_t)n * 128 + 64))[li];
    const float4 ratt = ((const float4*)att)[li];
    __syncthreads();

    float m = -INFINITY, l = 0.f;
    float4 acc = {0.f, 0.f, 0.f, 0.f};
    for (int j = g; j < deg; j += 4) {
        int s = scol[j];
        float4 xv = ((const float4*)(xlr + (size_t)s * 128))[li];
        float vx = xv.x + rxr.x; vx = (vx > 0.f) ? vx : LRELU * vx;
        float vy = xv.y + rxr.y; vy = (vy > 0.f) ? vy : LRELU * vy;
        float vz = xv.z + rxr.z; vz = (vz > 0.f) ? vz : LRELU * vz;
        float vw = xv.w + rxr.w; vw = (vw > 0.f) ? vw : LRELU * vw;
        float p = vx * ratt.x + vy * ratt.y + vz * ratt.z + vw * ratt.w;
        p += __shfl_xor(p, 1, 64);
        p += __shfl_xor(p, 2, 64);
        p += __shfl_xor(p, 4, 64);
        p += __shfl_xor(p, 8, 64);
        float mn = fmaxf(m, p);
        float sc = __expf(m - mn);
        float ep = __expf(p - mn);
        l = l * sc + ep;
        acc.x = fmaf(acc.x, sc, ep * xv.x);
        acc.y = fmaf(acc.y, sc, ep * xv.y);
        acc.z = fmaf(acc.z, sc, ep * xv.z);
        acc.w = fmaf(acc.w, sc, ep * xv.w);
        m = mn;
    }
    smw[g][li] = m;
    slw[g][li] = l;
    sacc[g][li] = acc;
    __syncthreads();
    if (g == 0) {
        float m0 = smw[0][li], m1 = smw[1][li], m2 = smw[2][li], m3 = smw[3][li];
        float ms = fmaxf(fmaxf(m0, m1), fmaxf(m2, m3));
        float c0 = (m0 == -INFINITY) ? 0.f : __expf(m0 - ms);
        float c1 = (m1 == -INFINITY) ? 0.f : __expf(m1 - ms);
        float c2 = (m2 == -INFINITY) ? 0.f : __expf(m2 - ms);
        float c3 = (m3 == -INFINITY) ? 0.f : __expf(m3 - ms);
        float lt = slw[0][li] * c0 + slw[1][li] * c1 + slw[2][li] * c2 + slw[3][li] * c3;
        float rden = (lt > 0.f) ? 1.f / lt : 0.f;
        float4 a0 = sacc[0][li], a1 = sacc[1][li], a2 = sacc[2][li], a3 = sacc[3][li];
        float4 bv = ((const float4*)bias)[li];
        float4 o;
        o.x = (a0.x * c0 + a1.x * c1 + a2.x * c2 + a3.x * c3) * rden + bv.x;
        o.y = (a0.y * c0 + a1.y * c1 + a2.y * c2 + a3.y * c3) * rden + bv.y;
        o.z = (a0.z * c0 + a1.z * c1 + a2.z * c2 + a3.z * c3) * rden + bv.z;
        o.w = (a0.w * c0 + a1.w * c1 + a2.w * c2 + a3.w * c3) * rden + bv.w;
        ((float4*)(out + (size_t)n * 64))[li] = o;
        float s = o.x + o.y + o.z + o.w;
        float s2 = o.x * o.x + o.y * o.y + o.z * o.z + o.w * o.w;
        #pragma unroll
        for (int off = 8; off > 0; off >>= 1) {
            s  += __shfl_xor(s, off, 64);
            s2 += __shfl_xor(s2, off, 64);
        }
        if (li == 0) {
            int b = n & 63;
            atomicAdd(&bk[b * 4], s);
            atomicAdd(&bk[b * 4 + 1], s2);
        }
    }
}

// ---------------------------------------------------------------- LN apply + relu -> bf16 split (+opt fp32)
__global__ __launch_bounds__(256) void ln_split(const float* __restrict__ h,
                                                const float* __restrict__ bk, float invM,
                                                const float* __restrict__ g,
                                                const float* __restrict__ b,
                                                int M4, int mask,
                                                ushort* __restrict__ Oh,
                                                ushort* __restrict__ Ol,
                                                float* __restrict__ ofp) {
    __shared__ float sm[2];
    if (threadIdx.x == 0) {
        float s = 0.f, s2 = 0.f;
        for (int i = 0; i < 64; i++) { s += bk[i * 4]; s2 += bk[i * 4 + 1]; }
        float mu = s * invM;
        float var = s2 * invM - mu * mu;
        sm[0] = mu;
        sm[1] = rsqrtf(var + LN_EPS);
    }
    __syncthreads();
    int i = blockIdx.x * 256 + threadIdx.x;
    if (i >= M4) return;
    float mu = sm[0], rstd = sm[1];
    int c = (i * 4) & mask;
    float4 v = ((const float4*)h)[i];
    float4 gg = *(const float4*)&g[c];
    float4 bb = *(const float4*)&b[c];
    v.x = fmaxf((v.x - mu) * rstd * gg.x + bb.x, 0.f);
    v.y = fmaxf((v.y - mu) * rstd * gg.y + bb.y, 0.f);
    v.z = fmaxf((v.z - mu) * rstd * gg.z + bb.z, 0.f);
    v.w = fmaxf((v.w - mu) * rstd * gg.w + bb.w, 0.f);
    if (ofp) ((float4*)ofp)[i] = v;
    ushort4 hh, ll;
    split_bf16(v.x, hh.x, ll.x);
    split_bf16(v.y, hh.y, ll.y);
    split_bf16(v.z, hh.z, ll.z);
    split_bf16(v.w, hh.w, ll.w);
    ((ushort4*)Oh)[i] = hh;
    ((ushort4*)Ol)[i] = ll;
}

// ---------------------------------------------------------------- final LN + relu + residual + pool
__global__ __launch_bounds__(256) void ln_pool(const float* __restrict__ G,
                                               const float* __restrict__ bk, float invM,
                                               const float* __restrict__ g,
                                               const float* __restrict__ b,
                                               const float* __restrict__ res,
                                               const int* __restrict__ batch,
                                               float* __restrict__ Zsum) {
    __shared__ float sm[2];
    if (threadIdx.x == 0) {
        float s = 0.f, s2 = 0.f;
        for (int i = 0; i < 64; i++) { s += bk[i * 4]; s2 += bk[i * 4 + 1]; }
        float mu = s * invM;
        float var = s2 * invM - mu * mu;
        sm[0] = mu;
        sm[1] = rsqrtf(var + LN_EPS);
    }
    __syncthreads();
    int i = blockIdx.x * 256 + threadIdx.x;
    if (i >= NN * 16) return;   // float4 units
    float mu = sm[0], rstd = sm[1];
    int n = i >> 4, c4 = (i & 15) * 4;
    float4 v = ((const float4*)G)[i];
    float4 gg = *(const float4*)&g[c4];
    float4 bb = *(const float4*)&b[c4];
    float4 rr = ((const float4*)res)[i];
    v.x = fmaxf((v.x - mu) * rstd * gg.x + bb.x, 0.f) + rr.x;
    v.y = fmaxf((v.y - mu) * rstd * gg.y + bb.y, 0.f) + rr.y;
    v.z = fmaxf((v.z - mu) * rstd * gg.z + bb.z, 0.f) + rr.z;
    v.w = fmaxf((v.w - mu) * rstd * gg.w + bb.w, 0.f) + rr.w;
    int gr = batch[n];
    atomicAdd(&Zsum[gr * 64 + c4 + 0], v.x);
    atomicAdd(&Zsum[gr * 64 + c4 + 1], v.y);
    atomicAdd(&Zsum[gr * 64 + c4 + 2], v.z);
    atomicAdd(&Zsum[gr * 64 + c4 + 3], v.w);
}

// ---------------------------------------------------------------- MLP head
__global__ __launch_bounds__(64) void mlp_head(const float* __restrict__ Zsum,
                                               const int* __restrict__ gcount,
                                               const float* __restrict__ Wh1,
                                               const float* __restrict__ bh1,
                                               const float* __restrict__ Wh2,
                                               const float* __restrict__ bh2,
                                               float* __restrict__ out) {
    __shared__ float sz[64];
    int g = blockIdx.x, tid = threadIdx.x;
    int cnt = gcount[g];
    float inv = 1.f / (float)(cnt > 1 ? cnt : 1);
    sz[tid] = Zsum[g * 64 + tid] * inv;
    __syncthreads();
    float acc = bh1[tid];
    #pragma unroll
    for (int c = 0; c < 64; c++) acc = fmaf(sz[c], Wh1[c * 64 + tid], acc);
    acc = fmaxf(acc, 0.f);
    float v = acc * Wh2[tid];
    #pragma unroll
    for (int off = 32; off > 0; off >>= 1) v += __shfl_xor(v, off, 64);
    if (tid == 0) out[g] = v + bh2[0];
}

// ---------------------------------------------------------------- launch
extern "C" void kernel_launch(void* const* d_in, const int* in_sizes, int n_in,
                              void* d_out, int out_size, void* d_ws, size_t ws_size,
                              hipStream_t stream) {
    (void)in_sizes; (void)n_in; (void)out_size; (void)ws_size;
    const float* x     = (const float*)d_in[0];
    const int*   ei    = (const int*)d_in[1];
    const int*   batch = (const int*)d_in[2];
    const float* Wl0 = (const float*)d_in[3];  const float* bl0 = (const float*)d_in[4];
    const float* Wr0 = (const float*)d_in[5];  const float* br0 = (const float*)d_in[6];
    const float* at0 = (const float*)d_in[7];  const float* bi0 = (const float*)d_in[8];
    const float* lg0 = (const float*)d_in[9];  const float* lb0 = (const float*)d_in[10];
    const float* Wl1 = (const float*)d_in[11]; const float* bl1 = (const float*)d_in[12];
    const float* Wr1 = (const float*)d_in[13]; const float* br1 = (const float*)d_in[14];
    const float* at1 = (const float*)d_in[15]; const float* bi1 = (const float*)d_in[16];
    const float* lg1 = (const float*)d_in[17]; const float* lb1 = (const float*)d_in[18];
    const float* Wl2 = (const float*)d_in[19]; const float* bl2 = (const float*)d_in[20];
    const float* Wr2 = (const float*)d_in[21]; const float* br2 = (const float*)d_in[22];
    const float* at2 = (const float*)d_in[23]; const float* bi2 = (const float*)d_in[24];
    const float* lg2 = (const float*)d_in[25]; const float* lb2 = (const float*)d_in[26];
    const float* Wh1 = (const float*)d_in[27]; const float* bh1 = (const float*)d_in[28];
    const float* Wh2 = (const float*)d_in[29]; const float* bh2 = (const float*)d_in[30];
    float* out = (float*)d_out;

    const int* srcp = ei;
    const int* dstp = ei + NE;

    char* w = (char*)d_ws;
    size_t off = 0;
    auto carve = [&](size_t bytes) -> void* {
        void* p = w + off;
        off += (bytes + 255) & ~(size_t)255;
        return p;
    };
    float*  AB = (float*)carve((size_t)NN * 512 * 4);       // GEMM outputs (xl|xr)
    float*  C  = (float*)carve((size_t)NN * 256 * 4);       // gat4 out fp32; later aliased
    float*  D  = (float*)carve((size_t)NN * 64 * 4);        // gat1 layer-1 out fp32
    ushort* S  = (ushort*)carve((size_t)NN * 256 * 2 * 2);  // bf16 planes: X (25.6MB) then E (51.2MB)
    ushort* wt = (ushort*)carve(212992 * 2);                // split-bf16 stacked weights
    size_t zbytes = 3 * 64 * 4 * 4 + (size_t)NG * 64 * 4 + NG * 4 + (size_t)NN * 4;
    char* zb = (char*)carve(zbytes);
    float* bk0 = (float*)zb;
    float* bk1 = bk0 + 64 * 4;
    float* bk2 = bk1 + 64 * 4;
    float* Zsum = (float*)(zb + 3 * 64 * 4 * 4);
    int*   gcnt = (int*)((char*)Zsum + (size_t)NG * 64 * 4);
    int*   deg  = (int*)((char*)gcnt + NG * 4);
    int* row_ptr = (int*)carve((size_t)(NN + 1) * 4);
    int* cursor  = (int*)carve((size_t)NN * 4);
    int* col_src = (int*)carve((size_t)NE * 4);
    int* bsum    = (int*)carve(64 * 4);

    // aliases
    ushort* Xh = S;                     // [NN][128]
    ushort* Xl = S + (size_t)NN * 128;
    ushort* Eh = S;                     // [NN][256]  (X dead after gemm0)
    ushort* El = S + (size_t)NN * 256;
    float*  G  = C;                     // [NN][64]   (C dead after ln0)
    float*  Dn = C + (size_t)NN * 64;   // fp32 ln1 out (residual source)
    ushort* Fh = (ushort*)(C + (size_t)NN * 128);   // [NN][64] planes
    ushort* Fl = Fh + (size_t)NN * 64;

    const ushort* W0h = wt;            const ushort* W0l = wt + 65536;
    const ushort* W1h = wt + 131072;   const ushort* W1l = wt + 163840;
    const ushort* W2h = wt + 196608;   const ushort* W2l = wt + 204800;

    hipMemsetAsync(zb, 0, zbytes, stream);
    prep_w<<<416, 256, 0, stream>>>(Wl0, Wr0, Wl1, Wr1, Wl2, Wr2, wt);
    split_x<<<(NN * 32 + 255) / 256, 256, 0, stream>>>(x, Xh, Xl);

    // CSR build (sort edges by dst) + graph counts
    hist_kernel<<<(NE + 255) / 256, 256, 0, stream>>>(dstp, deg);
    const int SB = (NN + 1023) / 1024;  // 49
    scan1<<<SB, 1024, 0, stream>>>(deg, row_ptr, bsum, NN);
    scan2<<<1, 1, 0, stream>>>(bsum, SB);
    scan3<<<SB, 1024, 0, stream>>>(row_ptr, cursor, bsum, NN);
    scatter_kernel<<<(NE + 255) / 256, 256, 0, stream>>>(srcp, dstp, cursor, col_src, batch, gcnt);

    const int GR = (NN + 127) / 128;  // 391
    const float invM0 = 1.f / ((float)NN * 256.f);
    const float invM1 = 1.f / ((float)NN * 64.f);

    // ---- layer 0: x[128] -> xl|xr[512]; GAT(H=4) -> C[256] (+bk0)
    gemm_bf16<<<dim3(GR, 4), 256, 0, stream>>>(Xh, Xl, W0h, W0l, bl0, br0, 256,
                                               AB, NN, 512, 128);
    gat4<<<NN, 256, 0, stream>>>(AB, at0, bi0, row_ptr, col_src, C, bk0);
    // LN0 + relu -> bf16 planes E
    ln_split<<<(NN * 64 + 255) / 256, 256, 0, stream>>>(C, bk0, invM0, lg0, lb0,
                                                        NN * 64, 255, Eh, El, nullptr);

    // ---- layer 1: E[256] -> xl|xr[128]; GAT -> D (+bk1)
    gemm_bf16<<<dim3(GR, 1), 256, 0, stream>>>(Eh, El, W1h, W1l, bl1, br1, 64,
                                               AB, NN, 128, 256);
    gat1<<<NN, 64, 0, stream>>>(AB, at1, bi1, row_ptr, col_src, D, bk1);
    // LN1 + relu -> Dn fp32 (residual) + bf16 planes F
    ln_split<<<(NN * 16 + 255) / 256, 256, 0, stream>>>(D, bk1, invM1, lg1, lb1,
                                                        NN * 16, 63, Fh, Fl, Dn);

    // ---- layer 2: F[64] -> xl|xr[128]; GAT -> G (+bk2); LN2+relu+residual+pool
    gemm_bf16<<<dim3(GR, 1), 256, 0, stream>>>(Fh, Fl, W2h, W2l, bl2, br2, 64,
                                               AB, NN, 128, 64);
    gat1<<<NN, 64, 0, stream>>>(AB, at2, bi2, row_ptr, col_src, G, bk2);
    ln_pool<<<(NN * 16 + 255) / 256, 256, 0, stream>>>(G, bk2, invM1, lg2, lb2,
                                                       Dn, batch, Zsum);

    // ---- MLP head
    mlp_head<<<NG, 64, 0, stream>>>(Zsum, gcnt, Wh1, bh1, Wh2, bh2, out);
}

// Round 6
// 937.530 us; speedup vs baseline: 1.0103x; 1.0103x over previous
//
#include <hip/hip_runtime.h>
#include <math.h>

#define NN 50000
#define NE 800000
#define NG 512
#define LRELU 0.2f
#define LN_EPS 1e-5f
#define GCAP 128   // max supported in-degree (data Poisson(16), max ~45)

typedef __attribute__((ext_vector_type(8))) short short8;
typedef __attribute__((ext_vector_type(4))) float f32x4;

__device__ inline float b2f(ushort u) { return __uint_as_float((unsigned)u << 16); }
__device__ inline ushort f2b(float v) {
    unsigned ub = __float_as_uint(v);
    return (ushort)((ub + 0x7FFFu + ((ub >> 16) & 1u)) >> 16);
}
__device__ inline void split_bf16(float v, ushort& h, ushort& l) {
    h = f2b(v);
    l = f2b(v - b2f(h));
}

// ---------------------------------------------------------------- CSR build
__global__ void hist_kernel(const int* __restrict__ dst, int* __restrict__ deg) {
    int e = blockIdx.x * blockDim.x + threadIdx.x;
    if (e < NE) atomicAdd(&deg[dst[e]], 1);
}

__global__ __launch_bounds__(1024) void scan1(const int* __restrict__ deg,
                                              int* __restrict__ excl,
                                              int* __restrict__ bsum, int n) {
    __shared__ int s[1024];
    int tid = threadIdx.x;
    int gid = blockIdx.x * 1024 + tid;
    int v = (gid < n) ? deg[gid] : 0;
    s[tid] = v;
    __syncthreads();
    for (int off = 1; off < 1024; off <<= 1) {
        int t = (tid >= off) ? s[tid - off] : 0;
        __syncthreads();
        s[tid] += t;
        __syncthreads();
    }
    if (gid < n) excl[gid] = s[tid] - v;
    if (tid == 1023) bsum[blockIdx.x] = s[1023];
}

__global__ __launch_bounds__(64) void scan2(int* __restrict__ bsum, int nb) {
    int tid = threadIdx.x;
    int orig = (tid < nb) ? bsum[tid] : 0;
    int v = orig;
    #pragma unroll
    for (int off = 1; off < 64; off <<= 1) {
        int t = __shfl_up(v, off, 64);
        if (tid >= off) v += t;
    }
    if (tid < nb) bsum[tid] = v - orig;   // exclusive
}

__global__ __launch_bounds__(1024) void scan3(int* __restrict__ row_ptr,
                                              int* __restrict__ cursor,
                                              const int* __restrict__ bsum, int n) {
    int tid = threadIdx.x;
    int gid = blockIdx.x * 1024 + tid;
    if (gid < n) {
        int v = row_ptr[gid] + bsum[blockIdx.x];
        row_ptr[gid] = v;
        cursor[gid] = v;
    }
    if (gid == 0) row_ptr[n] = NE;
}

__global__ void scatter_kernel(const int* __restrict__ src, const int* __restrict__ dst,
                               int* __restrict__ cursor, int* __restrict__ col_src,
                               const int* __restrict__ batch, int* __restrict__ gcnt) {
    int e = blockIdx.x * blockDim.x + threadIdx.x;
    if (e < NE) {
        int pos = atomicAdd(&cursor[dst[e]], 1);
        col_src[pos] = src[e];
    }
    if (e < NN) atomicAdd(&gcnt[batch[e]], 1);
}

// ---------------------------------------------------------------- weight / input prep
__global__ __launch_bounds__(256) void prep_w(const float* __restrict__ Wl0,
                                              const float* __restrict__ Wr0,
                                              const float* __restrict__ Wl1,
                                              const float* __restrict__ Wr1,
                                              const float* __restrict__ Wl2,
                                              const float* __restrict__ Wr2,
                                              ushort* __restrict__ wt) {
    int id = blockIdx.x * 256 + threadIdx.x;
    const float* Wl; const float* Wr; int K, half, rel; ushort* hi; int losz;
    if (id < 65536) {                    // layer 0: K=128, N=512 (256+256)
        rel = id; K = 128; half = 256; Wl = Wl0; Wr = Wr0;
        hi = wt; losz = 65536;
    } else if (id < 98304) {             // layer 1: K=256, N=128 (64+64)
        rel = id - 65536; K = 256; half = 64; Wl = Wl1; Wr = Wr1;
        hi = wt + 131072; losz = 32768;
    } else if (id < 106496) {            // layer 2: K=64, N=128 (64+64)
        rel = id - 98304; K = 64; half = 64; Wl = Wl2; Wr = Wr2;
        hi = wt + 196608; losz = 8192;
    } else return;
    int n = rel / K, k = rel - n * K;
    float v = (n < half) ? Wl[k * half + n] : Wr[k * half + (n - half)];
    ushort h, l;
    split_bf16(v, h, l);
    hi[rel] = h;
    hi[losz + rel] = l;
}

__global__ __launch_bounds__(256) void split_x(const float* __restrict__ x,
                                               ushort* __restrict__ Xh,
                                               ushort* __restrict__ Xl) {
    int i = blockIdx.x * 256 + threadIdx.x;
    if (i >= NN * 32) return;   // float4 units
    float4 v = ((const float4*)x)[i];
    ushort4 h, l;
    split_bf16(v.x, h.x, l.x);
    split_bf16(v.y, h.y, l.y);
    split_bf16(v.z, h.z, l.z);
    split_bf16(v.w, h.w, l.w);
    ((ushort4*)Xh)[i] = h;
    ((ushort4*)Xl)[i] = l;
}

// ---------------------------------------------------------------- MFMA GEMM (bf16 hi/lo planes)
// C = (Ah+Al)@(Bh+Bl)^T + bias ; 128x128 block tile, 4 waves 2x2 of 64x64.
// Also writes a bf16 (RNE) copy of cols < bfN to Xb [M][bfN] for the gather kernels.
template <int LID>
__global__ __launch_bounds__(256) void gemm_l(const ushort* __restrict__ Ah,
                                              const ushort* __restrict__ Al,
                                              const ushort* __restrict__ Bh,
                                              const ushort* __restrict__ Bl,
                                              const float* __restrict__ biasL,
                                              const float* __restrict__ biasR,
                                              int halfN,
                                              float* __restrict__ C,
                                              int M, int Ncol, int K,
                                              ushort* __restrict__ Xb, int bfN) {
    __shared__ ushort sA[2][128][40];
    __shared__ ushort sB[2][128][40];
    const int tid = threadIdx.x;
    const int w = tid >> 6, lane = tid & 63;
    const int row0 = blockIdx.x * 128;
    const int col0 = blockIdx.y * 128;
    const int wr = (w & 1) * 64, wc = (w >> 1) * 64;
    const int fm = lane & 15;
    const int fk8 = (lane >> 4) * 8;
    f32x4 acc[4][4] = {};

    for (int k0 = 0; k0 < K; k0 += 32) {
        __syncthreads();
        #pragma unroll
        for (int p = 0; p < 2; p++) {
            const ushort* Ap = p ? Al : Ah;
            const ushort* Bp = p ? Bl : Bh;
            #pragma unroll
            for (int it = 0; it < 2; it++) {
                int idx = it * 256 + tid;
                int r = idx >> 2, q = (idx & 3) * 8;
                int grow = row0 + r;
                short8 va = {};
                if (grow < M) va = *(const short8*)&Ap[(size_t)grow * K + k0 + q];
                *(short8*)&sA[p][r][q] = va;
                *(short8*)&sB[p][r][q] = *(const short8*)&Bp[(size_t)(col0 + r) * K + k0 + q];
            }
        }
        __syncthreads();
        short8 ah[4], al[4];
        #pragma unroll
        for (int m = 0; m < 4; m++) {
            ah[m] = *(const short8*)&sA[0][wr + m * 16 + fm][fk8];
            al[m] = *(const short8*)&sA[1][wr + m * 16 + fm][fk8];
        }
        #pragma unroll
        for (int c = 0; c < 4; c++) {
            short8 bh = *(const short8*)&sB[0][wc + c * 16 + fm][fk8];
            short8 bl = *(const short8*)&sB[1][wc + c * 16 + fm][fk8];
            #pragma unroll
            for (int m = 0; m < 4; m++) {
                acc[m][c] = __builtin_amdgcn_mfma_f32_16x16x32_bf16(ah[m], bh, acc[m][c], 0, 0, 0);
                acc[m][c] = __builtin_amdgcn_mfma_f32_16x16x32_bf16(al[m], bh, acc[m][c], 0, 0, 0);
                acc[m][c] = __builtin_amdgcn_mfma_f32_16x16x32_bf16(ah[m], bl, acc[m][c], 0, 0, 0);
            }
        }
    }
    // epilogue: C/D layout col=lane&15, row=(lane>>4)*4+reg
    const int rbase = (lane >> 4) * 4;
    #pragma unroll
    for (int c = 0; c < 4; c++) {
        int col = col0 + wc + c * 16 + fm;
        float bv = (col < halfN) ? biasL[col] : biasR[col - halfN];
        #pragma unroll
        for (int m = 0; m < 4; m++) {
            #pragma unroll
            for (int r = 0; r < 4; r++) {
                int grow = row0 + wr + m * 16 + rbase + r;
                if (grow < M) {
                    float val = acc[m][c][r] + bv;
                    C[(size_t)grow * Ncol + col] = val;
                    if (col < bfN) Xb[(size_t)grow * bfN + col] = f2b(val);
                }
            }
        }
    }
}

// ---------------------------------------------------------------- fused GATv2, H=4 (HC=256)
// bf16 gather of xl (512 B/edge); online softmax; fused LN-stat buckets.
__global__ __launch_bounds__(256) void gat4(const ushort* __restrict__ xb,   // [N][256] bf16 xl
                                            const float* __restrict__ xlr,   // [N][512], xr at +256
                                            const float* __restrict__ att,
                                            const float* __restrict__ bias,
                                            const int* __restrict__ row_ptr,
                                            const int* __restrict__ col_src,
                                            float* __restrict__ out,
                                            float* __restrict__ bk) {
    __shared__ float4 sxr[64];
    __shared__ float4 satt[64];
    __shared__ int    scol[GCAP];
    __shared__ float  smw[4][64];
    __shared__ float  slw[4][64];
    __shared__ float4 sacc[4][64];
    const int n = blockIdx.x;
    const int tid = threadIdx.x;
    const int w = tid >> 6, lane = tid & 63;
    const int base = row_ptr[n];
    int deg = row_ptr[n + 1] - base;
    if (deg > GCAP) deg = GCAP;
    if (tid < 64) {
        sxr[tid]  = ((const float4*)(xlr + (size_t)n * 512 + 256))[tid];
        satt[tid] = ((const float4*)att)[tid];
    }
    if (tid < deg) scol[tid] = col_src[base + tid];
    __syncthreads();
    const float4 rxr = sxr[lane], ratt = satt[lane];

    float m = -INFINITY, l = 0.f;
    float4 acc = {0.f, 0.f, 0.f, 0.f};
    for (int j = w; j < deg; j += 4) {
        int s = scol[j];
        ushort4 u = ((const ushort4*)(xb + (size_t)s * 256))[lane];
        float4 xv = {b2f(u.x), b2f(u.y), b2f(u.z), b2f(u.w)};
        float vx = xv.x + rxr.x; vx = (vx > 0.f) ? vx : LRELU * vx;
        float vy = xv.y + rxr.y; vy = (vy > 0.f) ? vy : LRELU * vy;
        float vz = xv.z + rxr.z; vz = (vz > 0.f) ? vz : LRELU * vz;
        float vw = xv.w + rxr.w; vw = (vw > 0.f) ? vw : LRELU * vw;
        float p = vx * ratt.x + vy * ratt.y + vz * ratt.z + vw * ratt.w;
        p += __shfl_xor(p, 1, 64);
        p += __shfl_xor(p, 2, 64);
        p += __shfl_xor(p, 4, 64);
        p += __shfl_xor(p, 8, 64);
        float mn = fmaxf(m, p);
        float sc = __expf(m - mn);
        float ep = __expf(p - mn);
        l = l * sc + ep;
        acc.x = fmaf(acc.x, sc, ep * xv.x);
        acc.y = fmaf(acc.y, sc, ep * xv.y);
        acc.z = fmaf(acc.z, sc, ep * xv.z);
        acc.w = fmaf(acc.w, sc, ep * xv.w);
        m = mn;
    }
    smw[w][lane] = m;
    slw[w][lane] = l;
    sacc[w][lane] = acc;
    __syncthreads();
    if (w == 0) {
        float m0 = smw[0][lane], m1 = smw[1][lane], m2 = smw[2][lane], m3 = smw[3][lane];
        float ms = fmaxf(fmaxf(m0, m1), fmaxf(m2, m3));
        float c0 = (m0 == -INFINITY) ? 0.f : __expf(m0 - ms);
        float c1 = (m1 == -INFINITY) ? 0.f : __expf(m1 - ms);
        float c2 = (m2 == -INFINITY) ? 0.f : __expf(m2 - ms);
        float c3 = (m3 == -INFINITY) ? 0.f : __expf(m3 - ms);
        float lt = slw[0][lane] * c0 + slw[1][lane] * c1 + slw[2][lane] * c2 + slw[3][lane] * c3;
        float rden = (lt > 0.f) ? 1.f / lt : 0.f;
        float4 a0 = sacc[0][lane], a1 = sacc[1][lane], a2 = sacc[2][lane], a3 = sacc[3][lane];
        float4 bv = ((const float4*)bias)[lane];
        float4 o;
        o.x = (a0.x * c0 + a1.x * c1 + a2.x * c2 + a3.x * c3) * rden + bv.x;
        o.y = (a0.y * c0 + a1.y * c1 + a2.y * c2 + a3.y * c3) * rden + bv.y;
        o.z = (a0.z * c0 + a1.z * c1 + a2.z * c2 + a3.z * c3) * rden + bv.z;
        o.w = (a0.w * c0 + a1.w * c1 + a2.w * c2 + a3.w * c3) * rden + bv.w;
        ((float4*)(out + (size_t)n * 256))[lane] = o;
        float s = o.x + o.y + o.z + o.w;
        float s2 = o.x * o.x + o.y * o.y + o.z * o.z + o.w * o.w;
        #pragma unroll
        for (int off = 32; off > 0; off >>= 1) {
            s  += __shfl_xor(s, off, 64);
            s2 += __shfl_xor(s2, off, 64);
        }
        if (lane == 0) {
            int b = n & 63;
            atomicAdd(&bk[b * 4], s);
            atomicAdd(&bk[b * 4 + 1], s2);
        }
    }
}

// ---------------------------------------------------------------- fused GATv2, H=1 (HC=64)
template <int LID>
__global__ __launch_bounds__(64) void gat1_l(const ushort* __restrict__ xb,   // [N][64] bf16 xl
                                             const float* __restrict__ xlr,   // [N][128], xr at +64
                                             const float* __restrict__ att,
                                             const float* __restrict__ bias,
                                             const int* __restrict__ row_ptr,
                                             const int* __restrict__ col_src,
                                             float* __restrict__ out,
                                             float* __restrict__ bk) {
    __shared__ int    scol[GCAP];
    __shared__ float  smw[4][16];
    __shared__ float  slw[4][16];
    __shared__ float4 sacc[4][16];
    const int n = blockIdx.x;
    const int lane = threadIdx.x;
    const int base = row_ptr[n];
    int deg = row_ptr[n + 1] - base;
    if (deg > GCAP) deg = GCAP;
    for (int j = lane; j < deg; j += 64) scol[j] = col_src[base + j];
    const int g = lane >> 4, li = lane & 15;
    const float4 rxr  = ((const float4*)(xlr + (size_t)n * 128 + 64))[li];
    const float4 ratt = ((const float4*)att)[li];
    __syncthreads();

    float m = -INFINITY, l = 0.f;
    float4 acc = {0.f, 0.f, 0.f, 0.f};
    for (int j = g; j < deg; j += 4) {
        int s = scol[j];
        ushort4 u = ((const ushort4*)(xb + (size_t)s * 64))[li];
        float4 xv = {b2f(u.x), b2f(u.y), b2f(u.z), b2f(u.w)};
        float vx = xv.x + rxr.x; vx = (vx > 0.f) ? vx : LRELU * vx;
        float vy = xv.y + rxr.y; vy = (vy > 0.f) ? vy : LRELU * vy;
        float vz = xv.z + rxr.z; vz = (vz > 0.f) ? vz : LRELU * vz;
        float vw = xv.w + rxr.w; vw = (vw > 0.f) ? vw : LRELU * vw;
        float p = vx * ratt.x + vy * ratt.y + vz * ratt.z + vw * ratt.w;
        p += __shfl_xor(p, 1, 64);
        p += __shfl_xor(p, 2, 64);
        p += __shfl_xor(p, 4, 64);
        p += __shfl_xor(p, 8, 64);
        float mn = fmaxf(m, p);
        float sc = __expf(m - mn);
        float ep = __expf(p - mn);
        l = l * sc + ep;
        acc.x = fmaf(acc.x, sc, ep * xv.x);
        acc.y = fmaf(acc.y, sc, ep * xv.y);
        acc.z = fmaf(acc.z, sc, ep * xv.z);
        acc.w = fmaf(acc.w, sc, ep * xv.w);
        m = mn;
    }
    smw[g][li] = m;
    slw[g][li] = l;
    sacc[g][li] = acc;
    __syncthreads();
    if (g == 0) {
        float m0 = smw[0][li], m1 = smw[1][li], m2 = smw[2][li], m3 = smw[3][li];
        float ms = fmaxf(fmaxf(m0, m1), fmaxf(m2, m3));
        float c0 = (m0 == -INFINITY) ? 0.f : __expf(m0 - ms);
        float c1 = (m1 == -INFINITY) ? 0.f : __expf(m1 - ms);
        float c2 = (m2 == -INFINITY) ? 0.f : __expf(m2 - ms);
        float c3 = (m3 == -INFINITY) ? 0.f : __expf(m3 - ms);
        float lt = slw[0][li] * c0 + slw[1][li] * c1 + slw[2][li] * c2 + slw[3][li] * c3;
        float rden = (lt > 0.f) ? 1.f / lt : 0.f;
        float4 a0 = sacc[0][li], a1 = sacc[1][li], a2 = sacc[2][li], a3 = sacc[3][li];
        float4 bv = ((const float4*)bias)[li];
        float4 o;
        o.x = (a0.x * c0 + a1.x * c1 + a2.x * c2 + a3.x * c3) * rden + bv.x;
        o.y = (a0.y * c0 + a1.y * c1 + a2.y * c2 + a3.y * c3) * rden + bv.y;
        o.z = (a0.z * c0 + a1.z * c1 + a2.z * c2 + a3.z * c3) * rden + bv.z;
        o.w = (a0.w * c0 + a1.w * c1 + a2.w * c2 + a3.w * c3) * rden + bv.w;
        ((float4*)(out + (size_t)n * 64))[li] = o;
        float s = o.x + o.y + o.z + o.w;
        float s2 = o.x * o.x + o.y * o.y + o.z * o.z + o.w * o.w;
        #pragma unroll
        for (int off = 8; off > 0; off >>= 1) {
            s  += __shfl_xor(s, off, 64);
            s2 += __shfl_xor(s2, off, 64);
        }
        if (li == 0) {
            int b = n & 63;
            atomicAdd(&bk[b * 4], s);
            atomicAdd(&bk[b * 4 + 1], s2);
        }
    }
}

// ---------------------------------------------------------------- LN apply + relu -> bf16 split (+opt fp32)
template <int LID>
__global__ __launch_bounds__(256) void ln_split(const float* __restrict__ h,
                                                const float* __restrict__ bk, float invM,
                                                const float* __restrict__ g,
                                                const float* __restrict__ b,
                                                int M4, int mask,
                                                ushort* __restrict__ Oh,
                                                ushort* __restrict__ Ol,
                                                float* __restrict__ ofp) {
    __shared__ float sm[2];
    if (threadIdx.x == 0) {
        float s = 0.f, s2 = 0.f;
        for (int i = 0; i < 64; i++) { s += bk[i * 4]; s2 += bk[i * 4 + 1]; }
        float mu = s * invM;
        float var = s2 * invM - mu * mu;
        sm[0] = mu;
        sm[1] = rsqrtf(var + LN_EPS);
    }
    __syncthreads();
    int i = blockIdx.x * 256 + threadIdx.x;
    if (i >= M4) return;
    float mu = sm[0], rstd = sm[1];
    int c = (i * 4) & mask;
    float4 v = ((const float4*)h)[i];
    float4 gg = *(const float4*)&g[c];
    float4 bb = *(const float4*)&b[c];
    v.x = fmaxf((v.x - mu) * rstd * gg.x + bb.x, 0.f);
    v.y = fmaxf((v.y - mu) * rstd * gg.y + bb.y, 0.f);
    v.z = fmaxf((v.z - mu) * rstd * gg.z + bb.z, 0.f);
    v.w = fmaxf((v.w - mu) * rstd * gg.w + bb.w, 0.f);
    if (ofp) ((float4*)ofp)[i] = v;
    ushort4 hh, ll;
    split_bf16(v.x, hh.x, ll.x);
    split_bf16(v.y, hh.y, ll.y);
    split_bf16(v.z, hh.z, ll.z);
    split_bf16(v.w, hh.w, ll.w);
    ((ushort4*)Oh)[i] = hh;
    ((ushort4*)Ol)[i] = ll;
}

// ---------------------------------------------------------------- final LN + relu + residual + pool
__global__ __launch_bounds__(256) void ln_pool(const float* __restrict__ G,
                                               const float* __restrict__ bk, float invM,
                                               const float* __restrict__ g,
                                               const float* __restrict__ b,
                                               const float* __restrict__ res,
                                               const int* __restrict__ batch,
                                               float* __restrict__ Zsum) {
    __shared__ float sm[2];
    if (threadIdx.x == 0) {
        float s = 0.f, s2 = 0.f;
        for (int i = 0; i < 64; i++) { s += bk[i * 4]; s2 += bk[i * 4 + 1]; }
        float mu = s * invM;
        float var = s2 * invM - mu * mu;
        sm[0] = mu;
        sm[1] = rsqrtf(var + LN_EPS);
    }
    __syncthreads();
    int i = blockIdx.x * 256 + threadIdx.x;
    if (i >= NN * 16) return;
    float mu = sm[0], rstd = sm[1];
    int n = i >> 4, c4 = (i & 15) * 4;
    float4 v = ((const float4*)G)[i];
    float4 gg = *(const float4*)&g[c4];
    float4 bb = *(const float4*)&b[c4];
    float4 rr = ((const float4*)res)[i];
    v.x = fmaxf((v.x - mu) * rstd * gg.x + bb.x, 0.f) + rr.x;
    v.y = fmaxf((v.y - mu) * rstd * gg.y + bb.y, 0.f) + rr.y;
    v.z = fmaxf((v.z - mu) * rstd * gg.z + bb.z, 0.f) + rr.z;
    v.w = fmaxf((v.w - mu) * rstd * gg.w + bb.w, 0.f) + rr.w;
    int gr = batch[n];
    atomicAdd(&Zsum[gr * 64 + c4 + 0], v.x);
    atomicAdd(&Zsum[gr * 64 + c4 + 1], v.y);
    atomicAdd(&Zsum[gr * 64 + c4 + 2], v.z);
    atomicAdd(&Zsum[gr * 64 + c4 + 3], v.w);
}

// ---------------------------------------------------------------- MLP head
__global__ __launch_bounds__(64) void mlp_head(const float* __restrict__ Zsum,
                                               const int* __restrict__ gcount,
                                               const float* __restrict__ Wh1,
                                               const float* __restrict__ bh1,
                                               const float* __restrict__ Wh2,
                                               const float* __restrict__ bh2,
                                               float* __restrict__ out) {
    __shared__ float sz[64];
    int g = blockIdx.x, tid = threadIdx.x;
    int cnt = gcount[g];
    float inv = 1.f / (float)(cnt > 1 ? cnt : 1);
    sz[tid] = Zsum[g * 64 + tid] * inv;
    __syncthreads();
    float acc = bh1[tid];
    #pragma unroll
    for (int c = 0; c < 64; c++) acc = fmaf(sz[c], Wh1[c * 64 + tid], acc);
    acc = fmaxf(acc, 0.f);
    float v = acc * Wh2[tid];
    #pragma unroll
    for (int off = 32; off > 0; off >>= 1) v += __shfl_xor(v, off, 64);
    if (tid == 0) out[g] = v + bh2[0];
}

// ---------------------------------------------------------------- launch
extern "C" void kernel_launch(void* const* d_in, const int* in_sizes, int n_in,
                              void* d_out, int out_size, void* d_ws, size_t ws_size,
                              hipStream_t stream) {
    (void)in_sizes; (void)n_in; (void)out_size; (void)ws_size;
    const float* x     = (const float*)d_in[0];
    const int*   ei    = (const int*)d_in[1];
    const int*   batch = (const int*)d_in[2];
    const float* Wl0 = (const float*)d_in[3];  const float* bl0 = (const float*)d_in[4];
    const float* Wr0 = (const float*)d_in[5];  const float* br0 = (const float*)d_in[6];
    const float* at0 = (const float*)d_in[7];  const float* bi0 = (const float*)d_in[8];
    const float* lg0 = (const float*)d_in[9];  const float* lb0 = (const float*)d_in[10];
    const float* Wl1 = (const float*)d_in[11]; const float* bl1 = (const float*)d_in[12];
    const float* Wr1 = (const float*)d_in[13]; const float* br1 = (const float*)d_in[14];
    const float* at1 = (const float*)d_in[15]; const float* bi1 = (const float*)d_in[16];
    const float* lg1 = (const float*)d_in[17]; const float* lb1 = (const float*)d_in[18];
    const float* Wl2 = (const float*)d_in[19]; const float* bl2 = (const float*)d_in[20];
    const float* Wr2 = (const float*)d_in[21]; const float* br2 = (const float*)d_in[22];
    const float* at2 = (const float*)d_in[23]; const float* bi2 = (const float*)d_in[24];
    const float* lg2 = (const float*)d_in[25]; const float* lb2 = (const float*)d_in[26];
    const float* Wh1 = (const float*)d_in[27]; const float* bh1 = (const float*)d_in[28];
    const float* Wh2 = (const float*)d_in[29]; const float* bh2 = (const float*)d_in[30];
    float* out = (float*)d_out;

    const int* srcp = ei;
    const int* dstp = ei + NE;

    char* w = (char*)d_ws;
    size_t off = 0;
    auto carve = [&](size_t bytes) -> void* {
        void* p = w + off;
        off += (bytes + 255) & ~(size_t)255;
        return p;
    };
    float*  AB  = (float*)carve((size_t)NN * 512 * 4);       // gemm fp32 out (xl|xr)
    float*  C   = (float*)carve((size_t)NN * 256 * 4);       // gat4 out; later aliased
    float*  D   = (float*)carve((size_t)NN * 64 * 4);        // gat1<1> out
    ushort* S   = (ushort*)carve((size_t)NN * 256 * 2 * 2);  // hi/lo plane buffers
    ushort* Xb0 = (ushort*)carve((size_t)NN * 256 * 2);      // bf16 xl for gathers
    ushort* wt  = (ushort*)carve(212992 * 2);
    size_t zbytes = 3 * 64 * 4 * 4 + (size_t)NG * 64 * 4 + NG * 4 + (size_t)NN * 4;
    char* zb = (char*)carve(zbytes);
    float* bk0 = (float*)zb;
    float* bk1 = bk0 + 64 * 4;
    float* bk2 = bk1 + 64 * 4;
    float* Zsum = (float*)(zb + 3 * 64 * 4 * 4);
    int*   gcnt = (int*)((char*)Zsum + (size_t)NG * 64 * 4);
    int*   deg  = (int*)((char*)gcnt + NG * 4);
    int* row_ptr = (int*)carve((size_t)(NN + 1) * 4);
    int* cursor  = (int*)carve((size_t)NN * 4);
    int* col_src = (int*)carve((size_t)NE * 4);
    int* bsum    = (int*)carve(64 * 4);

    // aliases
    ushort* Xh = S;                     // [NN][128] input planes
    ushort* Xl = S + (size_t)NN * 128;
    ushort* Eh = S;                     // [NN][256] layer-0 activation planes (X dead)
    ushort* El = S + (size_t)NN * 256;
    float*  G  = C;                     // [NN][64] layer-2 gat out (C dead after ln_split<0>)
    float*  Dn = C + (size_t)NN * 64;   // fp32 ln1 out (residual)
    ushort* Fh = (ushort*)(C + (size_t)NN * 128);   // [NN][64] layer-1 activation planes
    ushort* Fl = Fh + (size_t)NN * 64;
    ushort* Xb1 = Xb0;                  // [NN][64] bf16 xl for layers 1/2 (Xb0 dead after gat4)

    const ushort* W0h = wt;            const ushort* W0l = wt + 65536;
    const ushort* W1h = wt + 131072;   const ushort* W1l = wt + 163840;
    const ushort* W2h = wt + 196608;   const ushort* W2l = wt + 204800;

    hipMemsetAsync(zb, 0, zbytes, stream);
    prep_w<<<416, 256, 0, stream>>>(Wl0, Wr0, Wl1, Wr1, Wl2, Wr2, wt);
    split_x<<<(NN * 32 + 255) / 256, 256, 0, stream>>>(x, Xh, Xl);

    // CSR build + graph counts
    hist_kernel<<<(NE + 255) / 256, 256, 0, stream>>>(dstp, deg);
    const int SB = (NN + 1023) / 1024;  // 49
    scan1<<<SB, 1024, 0, stream>>>(deg, row_ptr, bsum, NN);
    scan2<<<1, 64, 0, stream>>>(bsum, SB);
    scan3<<<SB, 1024, 0, stream>>>(row_ptr, cursor, bsum, NN);
    scatter_kernel<<<(NE + 255) / 256, 256, 0, stream>>>(srcp, dstp, cursor, col_src, batch, gcnt);

    const int GR = (NN + 127) / 128;  // 391
    const float invM0 = 1.f / ((float)NN * 256.f);
    const float invM1 = 1.f / ((float)NN * 64.f);

    // ---- layer 0
    gemm_l<0><<<dim3(GR, 4), 256, 0, stream>>>(Xh, Xl, W0h, W0l, bl0, br0, 256,
                                               AB, NN, 512, 128, Xb0, 256);
    gat4<<<NN, 256, 0, stream>>>(Xb0, AB, at0, bi0, row_ptr, col_src, C, bk0);
    ln_split<0><<<(NN * 64 + 255) / 256, 256, 0, stream>>>(C, bk0, invM0, lg0, lb0,
                                                           NN * 64, 255, Eh, El, nullptr);

    // ---- layer 1
    gemm_l<1><<<dim3(GR, 1), 256, 0, stream>>>(Eh, El, W1h, W1l, bl1, br1, 64,
                                               AB, NN, 128, 256, Xb1, 64);
    gat1_l<1><<<NN, 64, 0, stream>>>(Xb1, AB, at1, bi1, row_ptr, col_src, D, bk1);
    ln_split<1><<<(NN * 16 + 255) / 256, 256, 0, stream>>>(D, bk1, invM1, lg1, lb1,
                                                           NN * 16, 63, Fh, Fl, Dn);

    // ---- layer 2
    gemm_l<2><<<dim3(GR, 1), 256, 0, stream>>>(Fh, Fl, W2h, W2l, bl2, br2, 64,
                                               AB, NN, 128, 64, Xb1, 64);
    gat1_l<2><<<NN, 64, 0, stream>>>(Xb1, AB, at2, bi2, row_ptr, col_src, G, bk2);
    ln_pool<<<(NN * 16 + 255) / 256, 256, 0, stream>>>(G, bk2, invM1, lg2, lb2,
                                                       Dn, batch, Zsum);

    // ---- head
    mlp_head<<<NG, 64, 0, stream>>>(Zsum, gcnt, Wh1, bh1, Wh2, bh2, out);
}